// Round 6
// baseline (916.682 us; speedup 1.0000x reference)
//
#include <hip/hip_runtime.h>
#include <cstdint>
#include <cstddef>

#define Nn 40000
#define Ne 640000
#define CC 128
#define EPSbn 1e-5f

typedef __attribute__((ext_vector_type(8))) __bf16 bf16x8;
typedef __attribute__((ext_vector_type(4))) float floatx4;
typedef __attribute__((ext_vector_type(8))) unsigned short ushort8;

__device__ inline unsigned short f2bf(float x){
  union { float f; unsigned u; } c; c.f = x;
  unsigned r = c.u + 0x7fffu + ((c.u >> 16) & 1u);
  return (unsigned short)(r >> 16);
}
__device__ inline float bflo(unsigned u){ return __uint_as_float(u << 16); }
__device__ inline float bfhi(unsigned u){ return __uint_as_float(u & 0xffff0000u); }

// ---- fp8 e4m3fn encode (manual RNE; cold path, repack only) ----
__device__ inline unsigned f2e4m3(float x){
  unsigned u = __float_as_uint(x);
  unsigned s = (u >> 24) & 0x80u;
  unsigned a = u & 0x7fffffffu;
  unsigned lsb = (a >> 20) & 1u;
  a += 0x0007FFFFu + lsb;                  // RNE to 3 mantissa bits
  int e = (int)((a >> 23) & 0xffu) - 127;
  unsigned b;
  if (e < -9)      b = 0u;
  else if (e < -6) b = (unsigned)(int)rintf(__uint_as_float(u & 0x7fffffffu) * 512.f);
  else if (e > 8)  b = 0x7Eu;
  else             b = (unsigned)(((e + 7) << 3) | ((a >> 20) & 7u));
  if ((b & 0x7fu) == 0x7fu) b = 0x7Eu;     // avoid NaN encoding (e4m3fn)
  return s | b;
}

// ---- fp8 e4m3fn decode: HW builtin (1 op) with guarded fallback ----
#if defined(__has_builtin)
#if __has_builtin(__builtin_amdgcn_cvt_f32_fp8)
#define FP8_HW 1
#endif
#endif
template<int SEL>
__device__ inline float fp8dec(unsigned w){
#ifdef FP8_HW
  return __builtin_amdgcn_cvt_f32_fp8((int)w, SEL);
#else
  unsigned b = (w >> (SEL*8)) & 0xffu;
  unsigned s = (b & 0x80u) << 24;
  unsigned em = b & 0x7fu;
  float v;
  if (em >= 8) v = __uint_as_float((((em >> 3) + 117u) << 23)) * (float)(8 + (em & 7));
  else         v = (float)em * 0.001953125f;   // em * 2^-9
  return __uint_as_float(__float_as_uint(v) | s);
#endif
}

// ---- device-scope spin barrier for persistent kernels (graph-capture safe) ----
// SAFETY: caller grids are exactly 512 blocks = 2 blocks/CU x 256 CU, with
// static LDS <= 70.7KB (2x < 160KB) and __launch_bounds__(256,2) (VGPR<=256)
// => all blocks co-resident => no deadlock. Counters pre-zeroed by prep_k.
__device__ inline void gbar(int* c, int nb){
  __syncthreads();
  if (threadIdx.x == 0) {
    __threadfence();                      // release: my writes visible first
    atomicAdd(c, 1);
    while (atomicAdd(c, 0) < nb) __builtin_amdgcn_s_sleep(2);
  }
  __syncthreads();
  __threadfence();                        // acquire: see others' writes
}

// ---------------- prep: zero int scratch (incl. barrier counters) + weights->bf16 ----------------
__global__ __launch_bounds__(256) void prep_k(int* __restrict__ zp, int zn,
    const float* __restrict__ Wq, const float* __restrict__ Wk,
    const float* __restrict__ Wv, const float* __restrict__ Wo,
    const float* __restrict__ W1, const float* __restrict__ W2,
    unsigned short* __restrict__ Wb)
{
  int b = blockIdx.x, tid = threadIdx.x;
  if (b < 161) { int i = b*256 + tid; if (i < zn) zp[i] = 0; return; }
  int i = (b - 161)*256 + tid;          // 0..131071
  const float* s; int off;
  if      (i < 16384) { s = Wq; off = i; }
  else if (i < 32768) { s = Wk; off = i - 16384; }
  else if (i < 49152) { s = Wv; off = i - 32768; }
  else if (i < 65536) { s = Wo; off = i - 49152; }
  else if (i < 98304) { s = W1; off = i - 65536; }
  else                { s = W2; off = i - 98304; }
  Wb[i] = f2bf(s[off]);
}

// ---------------- GEMM tile (device fn): C = act(A' @ W^T + bias + res') ----------------
// mode: 0 = f32 out, 1 = bf16 out. Arithmetic byte-identical to the R5 mgemm_k.
template<int KTILES,bool ABF16,bool HASBIAS,bool HASRES,bool RELU,bool BNA,bool BNRES,bool BNSTAT>
__device__ __forceinline__ void gemm_tile(
    const void* Ap, const unsigned short* W, void* Cp, int mode,
    const float* bias, const float* res,
    const float* scb, const float* shb,
    float* bnS, float* bnQ,
    unsigned short* As, unsigned short* Ws,
    int row0, int col0, int M, int Ncols)
{
  constexpr int K = KTILES * 128;
  const int tid  = threadIdx.x;
  const int lane = tid & 63;
  const int wv   = tid >> 6;
  const int m    = lane & 15;
  const int quad = lane >> 4;

  floatx4 acc[2][8] = {};

  for (int kt = 0; kt < K; kt += 128) {
    #pragma unroll
    for (int it = 0; it < 8; ++it) {
      int s = tid + it*256;
      int r = s >> 4;
      int c = (s & 15) << 3;
      *(ushort8*)&Ws[r*136 + c] =
          *(const ushort8*)(W + (size_t)(col0 + r)*K + kt + c);
    }
    if (ABF16) {
      #pragma unroll
      for (int it = 0; it < 8; ++it) {
        int s = tid + it*256;
        int r = s >> 4;
        int c = (s & 15) << 3;
        int gr = row0 + r; if (gr >= M) gr = M - 1;
        *(ushort8*)&As[r*136 + c] =
            *(const ushort8*)((const unsigned short*)Ap + (size_t)gr*K + kt + c);
      }
    } else {
      #pragma unroll 4
      for (int it = 0; it < 16; ++it) {
        int s = tid + it*256;
        int r = s >> 5;
        int c = (s & 31) << 2;
        int gr = row0 + r; if (gr >= M) gr = M - 1;
        float4 a4 = *(const float4*)((const float*)Ap + (size_t)gr*K + kt + c);
        if (BNA) {
          a4.x = a4.x*scb[c  ] + shb[c  ];
          a4.y = a4.y*scb[c+1] + shb[c+1];
          a4.z = a4.z*scb[c+2] + shb[c+2];
          a4.w = a4.w*scb[c+3] + shb[c+3];
        }
        ushort4 ua;
        ua.x = f2bf(a4.x); ua.y = f2bf(a4.y); ua.z = f2bf(a4.z); ua.w = f2bf(a4.w);
        *(ushort4*)&As[r*136 + c] = ua;
      }
    }
    __syncthreads();
    #pragma unroll
    for (int ks = 0; ks < 4; ++ks) {
      int ko = ks*32 + quad*8;
      bf16x8 a0 = *(const bf16x8*)&As[(32*wv      + m)*136 + ko];
      bf16x8 a1 = *(const bf16x8*)&As[(32*wv + 16 + m)*136 + ko];
      #pragma unroll
      for (int j = 0; j < 8; ++j) {
        bf16x8 bj = *(const bf16x8*)&Ws[(16*j + m)*136 + ko];
        acc[0][j] = __builtin_amdgcn_mfma_f32_16x16x32_bf16(a0, bj, acc[0][j], 0, 0, 0);
        acc[1][j] = __builtin_amdgcn_mfma_f32_16x16x32_bf16(a1, bj, acc[1][j], 0, 0, 0);
      }
    }
    __syncthreads();
  }

  float bcol[8], scv[8], shv[8];
  #pragma unroll
  for (int j = 0; j < 8; ++j) {
    int gcol = col0 + 16*j + m;
    if (HASBIAS) bcol[j] = bias[gcol];
    if (BNRES) { scv[j] = scb[16*j + m]; shv[j] = shb[16*j + m]; }  // Ncols==128
  }
  float ps[8] = {}, pq[8] = {};
  #pragma unroll
  for (int rt = 0; rt < 2; ++rt) {
    #pragma unroll
    for (int rg = 0; rg < 4; ++rg) {
      int grow = row0 + 32*wv + 16*rt + quad*4 + rg;
      if (grow < M) {
        #pragma unroll
        for (int j = 0; j < 8; ++j) {
          int gcol = col0 + 16*j + m;
          float o = acc[rt][j][rg];
          if (HASBIAS) o += bcol[j];
          if (HASRES) {
            float rr = res[(size_t)grow*Ncols + gcol];
            if (BNRES) rr = rr*scv[j] + shv[j];
            o += rr;
          }
          if (RELU) o = fmaxf(o, 0.f);
          if (BNSTAT) { ps[j] += o; pq[j] += o*o; }
          if (mode == 0)      ((float*)Cp)[(size_t)grow*Ncols + gcol] = o;
          else                ((unsigned short*)Cp)[(size_t)grow*Ncols + gcol] = f2bf(o);
        }
      }
    }
  }
  if (BNSTAT) {
    float* sS = (float*)&As[0];        // reuse LDS (guarded by caller's loop-top sync)
    float* sQ = sS + 4*128;
    #pragma unroll
    for (int j = 0; j < 8; ++j) {
      float s = ps[j], qq = pq[j];
      s += __shfl_xor(s, 16); qq += __shfl_xor(qq, 16);
      s += __shfl_xor(s, 32); qq += __shfl_xor(qq, 32);
      if (quad == 0) { sS[wv*128 + 16*j + m] = s; sQ[wv*128 + 16*j + m] = qq; }
    }
    __syncthreads();
    if (wv == 0) {
      #pragma unroll
      for (int c = 0; c < 128; c += 64) {
        int cc = c + lane;
        float s  = sS[cc] + sS[128+cc] + sS[256+cc] + sS[384+cc];
        float qq = sQ[cc] + sQ[128+cc] + sQ[256+cc] + sQ[384+cc];
        atomicAdd(&bnS[col0 + cc], s);
        atomicAdd(&bnQ[col0 + cc], qq);
      }
    }
  }
}

// ============ persistent kernel 1: hist -> scan1 -> scan23 -> scatter -> proj ============
struct CsrArgs {
  const int *dst, *src;
  int *counts, *offsets, *cursor, *posA, *srcs, *bsums, *bars;
  const float *q, *k, *v;
  const unsigned short *WqB, *WkB, *WvB;
  void *QDb, *Kb, *Vb;
};

__global__ __launch_bounds__(256,2) void csr_k(CsrArgs a){
  __shared__ __align__(16) unsigned short As[128*136];
  __shared__ __align__(16) unsigned short Ws[128*136];
  const int tid = threadIdx.x, bid = blockIdx.x, nb = gridDim.x;   // nb == 512
  const int gtid = bid*256 + tid, gsz = nb*256;

  // ---- P0: histogram (counts pre-zeroed by prep_k) ----
  for (int i = gtid; i < Ne; i += gsz) atomicAdd(&a.counts[a.dst[i]], 1);
  gbar(a.bars + 0, nb);

  // ---- P1: block-level scan (blocks 0..39, 1024 counts each) ----
  if (bid < 40) {
    int* wt = (int*)Ws;
    int base = bid*1024 + tid*4;
    int v0 = (base   < Nn) ? a.counts[base  ] : 0;
    int v1 = (base+1 < Nn) ? a.counts[base+1] : 0;
    int v2 = (base+2 < Nn) ? a.counts[base+2] : 0;
    int v3 = (base+3 < Nn) ? a.counts[base+3] : 0;
    int t1 = v0+v1, t2 = t1+v2, t3 = t2+v3;
    int lane = tid & 63, w1 = tid >> 6;
    int x = t3;
    #pragma unroll
    for (int off = 1; off < 64; off <<= 1) {
      int y = __shfl_up(x, off);
      if (lane >= off) x += y;
    }
    if (lane == 63) wt[w1] = x;
    __syncthreads();
    int wbase = 0;
    #pragma unroll
    for (int w = 0; w < 4; ++w) if (w < w1) wbase += wt[w];
    int excl = wbase + x - t3;
    if (base   < Nn) a.offsets[base  ] = excl;
    if (base+1 < Nn) a.offsets[base+1] = excl + v0;
    if (base+2 < Nn) a.offsets[base+2] = excl + t1;
    if (base+3 < Nn) a.offsets[base+3] = excl + t2;
    if (tid == 255) a.bsums[bid] = wbase + x;
  }
  gbar(a.bars + 1, nb);

  // ---- P2: global offsets + cursor init (per-block redundant 40-scan) ----
  {
    int* sb = (int*)As;
    if (tid < 64) {
      int v = (tid < 40) ? a.bsums[tid] : 0;
      int x = v;
      #pragma unroll
      for (int off = 1; off < 64; off <<= 1) {
        int y = __shfl_up(x, off);
        if (tid >= off) x += y;
      }
      if (tid < 40) sb[tid] = x - v;     // exclusive
    }
    __syncthreads();
    for (int i = gtid; i < Nn; i += gsz) {
      int o = a.offsets[i] + sb[i >> 10];
      a.offsets[i] = o;
      a.cursor[i]  = o;
    }
    if (gtid == 0) a.offsets[Nn] = Ne;
  }
  gbar(a.bars + 2, nb);

  // ---- P3: scatter (no barrier before P4 — proj is independent of CSR) ----
  for (int i = gtid; i < Ne; i += gsz) {
    int p = atomicAdd(&a.cursor[a.dst[i]], 1);
    a.posA[i]  = p;
    a.srcs[p]  = a.src[i];
  }

  // ---- P4: Q/K/V projection GEMM (939 vtiles, grid-stride) ----
  for (int t = bid; t < 939; t += nb) {
    __syncthreads();                     // LDS reuse guard between vtiles/phases
    int z  = t / 313;
    int bx = t - z*313;
    const void* Ap = (z==0) ? (const void*)a.q : (z==1) ? (const void*)a.k : (const void*)a.v;
    const unsigned short* W = (z==0) ? a.WqB : (z==1) ? a.WkB : a.WvB;
    void* Cp = (z==0) ? a.QDb : (z==1) ? a.Kb : a.Vb;
    gemm_tile<1,false,false,false,false,false,false,false>(
        Ap, W, Cp, 1, nullptr, nullptr, nullptr, nullptr, nullptr, nullptr,
        As, Ws, bx*128, 0, Nn, 128);
  }
}

// ---------------- merged: repack (blocks 0..9999) + ebias (blocks 10000..29999) ----------------
__global__ __launch_bounds__(256) void re_k(
    const unsigned* __restrict__ Kb, const unsigned* __restrict__ Vb,
    unsigned* __restrict__ KV,
    const float* __restrict__ ef, const float* __restrict__ We,
    const float* __restrict__ be, const int* __restrict__ pos,
    unsigned short* __restrict__ EBs)
{
  __shared__ float efs[32][68];
  __shared__ float Wes[8][68];
  __shared__ float bes[8];
  int tid = threadIdx.x;
  int b = blockIdx.x;
  if (b < 10000) {
    int i = b*256 + tid;               // exactly Nn*64 = 2,560,000 items
    unsigned kk = Kb[i];
    unsigned vv = Vb[i];
    unsigned o = f2e4m3(bflo(kk)) | (f2e4m3(bfhi(kk)) << 8)
               | (f2e4m3(bflo(vv)) << 16) | (f2e4m3(bfhi(vv)) << 24);
    KV[i] = o;
    return;
  }
  // ---- ebias ----
  if (tid < 8) bes[tid] = be[tid];
  for (int i = tid; i < 512; i += 256) Wes[i>>6][i&63] = We[i];
  int e0 = (b - 10000) * 32;
  #pragma unroll
  for (int l = 0; l < 2; ++l) {
    int idx = tid + l*256;
    int r   = idx >> 4;
    int q4  = (idx & 15) << 2;
    float4 t = *(const float4*)(ef + (size_t)(e0 + r)*64 + q4);
    efs[r][q4]=t.x; efs[r][q4+1]=t.y; efs[r][q4+2]=t.z; efs[r][q4+3]=t.w;
  }
  __syncthreads();
  int h = tid & 7, el = tid >> 3;
  int e = e0 + el;
  float es = 0.f;
  #pragma unroll
  for (int kk = 0; kk < 64; kk += 4) {
    float4 a = *(const float4*)&efs[el][kk];
    float4 bq = *(const float4*)&Wes[h][kk];
    es += a.x*bq.x + a.y*bq.y + a.z*bq.z + a.w*bq.w;
  }
  EBs[(size_t)pos[e]*8 + h] = f2bf(es + bes[h]);
}

// ---------------- fused scores + segment softmax + aggregation ----------------
__global__ __launch_bounds__(256) void agg_k(
    const unsigned* __restrict__ QDb, const unsigned* __restrict__ KV,
    const unsigned short* __restrict__ EBs,
    const int* __restrict__ offsets, const int* __restrict__ srcs,
    unsigned* __restrict__ agg, int n)
{
  int wv = threadIdx.x >> 6, lane = threadIdx.x & 63;
  int node = blockIdx.x*4 + wv;
  if (node >= n) return;
  unsigned qt = QDb[(size_t)node*64 + lane];
  float q0 = bflo(qt) * 0.25f;
  float q1 = bfhi(qt) * 0.25f;
  int beg = offsets[node], end = offsets[node+1];
  int hoff = lane >> 3;
  float acc0 = 0.f, acc1 = 0.f, den = 0.f;
  for (int base = beg; base < end; base += 64) {
    int mrem = end - base; if (mrem > 64) mrem = 64;
    int ss = (lane < mrem) ? srcs[base + lane] : 0;
    int j = 0;
    for (; j + 4 <= mrem; j += 4) {
      int s0 = __shfl(ss, j);
      int s1 = __shfl(ss, j+1);
      int s2 = __shfl(ss, j+2);
      int s3 = __shfl(ss, j+3);
      unsigned kv0 = KV[(size_t)s0*64 + lane];
      unsigned kv1 = KV[(size_t)s1*64 + lane];
      unsigned kv2 = KV[(size_t)s2*64 + lane];
      unsigned kv3 = KV[(size_t)s3*64 + lane];
      float p0 = q0*fp8dec<0>(kv0) + q1*fp8dec<1>(kv0);
      float p1 = q0*fp8dec<0>(kv1) + q1*fp8dec<1>(kv1);
      float p2 = q0*fp8dec<0>(kv2) + q1*fp8dec<1>(kv2);
      float p3 = q0*fp8dec<0>(kv3) + q1*fp8dec<1>(kv3);
      p0 += __shfl_xor(p0, 1); p1 += __shfl_xor(p1, 1); p2 += __shfl_xor(p2, 1); p3 += __shfl_xor(p3, 1);
      p0 += __shfl_xor(p0, 2); p1 += __shfl_xor(p1, 2); p2 += __shfl_xor(p2, 2); p3 += __shfl_xor(p3, 2);
      p0 += __shfl_xor(p0, 4); p1 += __shfl_xor(p1, 4); p2 += __shfl_xor(p2, 4); p3 += __shfl_xor(p3, 4);
      float eb0 = __uint_as_float(((unsigned)EBs[(size_t)(base+j  )*8 + hoff]) << 16);
      float eb1 = __uint_as_float(((unsigned)EBs[(size_t)(base+j+1)*8 + hoff]) << 16);
      float eb2 = __uint_as_float(((unsigned)EBs[(size_t)(base+j+2)*8 + hoff]) << 16);
      float eb3 = __uint_as_float(((unsigned)EBs[(size_t)(base+j+3)*8 + hoff]) << 16);
      float w0 = __expf(p0 + eb0);    // softmax shift-invariant; fp32 exp safe (|s| small)
      float w1 = __expf(p1 + eb1);
      float w2 = __expf(p2 + eb2);
      float w3 = __expf(p3 + eb3);
      acc0 += w0*fp8dec<2>(kv0) + w1*fp8dec<2>(kv1) + w2*fp8dec<2>(kv2) + w3*fp8dec<2>(kv3);
      acc1 += w0*fp8dec<3>(kv0) + w1*fp8dec<3>(kv1) + w2*fp8dec<3>(kv2) + w3*fp8dec<3>(kv3);
      den  += (w0 + w1) + (w2 + w3);
    }
    for (; j < mrem; ++j) {
      int s0 = __shfl(ss, j);
      unsigned kv0 = KV[(size_t)s0*64 + lane];
      float p0 = q0*fp8dec<0>(kv0) + q1*fp8dec<1>(kv0);
      p0 += __shfl_xor(p0, 1);
      p0 += __shfl_xor(p0, 2);
      p0 += __shfl_xor(p0, 4);
      float eb0 = __uint_as_float(((unsigned)EBs[(size_t)(base+j)*8 + hoff]) << 16);
      float w0 = __expf(p0 + eb0);
      acc0 += w0*fp8dec<2>(kv0);
      acc1 += w0*fp8dec<3>(kv0);
      den  += w0;
    }
  }
  float inv = den > 0.f ? 1.f/den : 0.f;
  unsigned o = (unsigned)f2bf(acc0*inv) | ((unsigned)f2bf(acc1*inv) << 16);
  agg[(size_t)node*64 + lane] = o;
}

// ============ persistent kernel 2: Wo-GEMM -> FFN1 -> FFN2 -> BN2 apply ============
struct TailArgs {
  const void* AGGb; const unsigned short* WoB; float* RST; const float* q;
  const unsigned short* W1B; void* H1; const float* b1;
  const unsigned short* W2B; float* Y; const float* b2;
  float *sum1, *sq1, *sum2, *sq2;
  const float *g1, *bt1, *g2, *bt2;
  float* outp; int* bars;
};

__global__ __launch_bounds__(256,2) void tail_k(TailArgs a){
  __shared__ __align__(16) unsigned short As[128*136];
  __shared__ __align__(16) unsigned short Ws[128*136];
  __shared__ float scb[128], shb[128];
  const int tid = threadIdx.x, bid = blockIdx.x, nb = gridDim.x;   // nb == 512
  const int gtid = bid*256 + tid, gsz = nb*256;

  // ---- P0: RST = AGGb@Wo^T + q (+ BN1 stats into sum1/sq1) ----
  for (int t = bid; t < 313; t += nb) {
    __syncthreads();
    gemm_tile<1,true,false,true,false,false,false,true>(
        a.AGGb, a.WoB, a.RST, 0, nullptr, a.q, nullptr, nullptr,
        a.sum1, a.sq1, As, Ws, t*128, 0, Nn, 128);
  }
  gbar(a.bars + 0, nb);

  // ---- BN1 coefficients (identical formula to old bnfin/BNA path) ----
  if (tid < 128) {
    float mu  = a.sum1[tid] / (float)Nn;
    float var = a.sq1[tid] / (float)Nn - mu*mu;
    float s   = a.g1[tid] * rsqrtf(var + EPSbn);
    scb[tid] = s;
    shb[tid] = a.bt1[tid] - mu*s;
  }
  __syncthreads();

  // ---- P1: H1 = relu(bn1(RST)@W1^T + b1), bf16 [N,256] (626 vtiles) ----
  for (int t = bid; t < 626; t += nb) {
    __syncthreads();
    int by = t / 313, bx = t - by*313;
    gemm_tile<1,false,true,false,true,true,false,false>(
        a.RST, a.W1B, a.H1, 1, a.b1, nullptr, scb, shb,
        nullptr, nullptr, As, Ws, bx*128, by*128, Nn, 256);
  }
  gbar(a.bars + 1, nb);

  // ---- P2: Y = H1@W2^T + b2 + bn1(RST) (+ BN2 stats), K=256 ----
  for (int t = bid; t < 313; t += nb) {
    __syncthreads();
    gemm_tile<2,true,true,true,false,false,true,true>(
        a.H1, a.W2B, a.Y, 0, a.b2, a.RST, scb, shb,
        a.sum2, a.sq2, As, Ws, t*128, 0, Nn, 128);
  }
  gbar(a.bars + 2, nb);

  // ---- P3: BN2 finalize + apply ----
  if (tid < 128) {
    float mu  = a.sum2[tid] / (float)Nn;
    float var = a.sq2[tid] / (float)Nn - mu*mu;
    float s   = a.g2[tid] * rsqrtf(var + EPSbn);
    scb[tid] = s;
    shb[tid] = a.bt2[tid] - mu*s;
  }
  __syncthreads();
  int n4 = (Nn*CC) >> 2;
  for (int i = gtid; i < n4; i += gsz) {
    float4 vv = ((const float4*)a.Y)[i];
    int c = (i << 2) & 127;
    vv.x = vv.x*scb[c  ] + shb[c  ];
    vv.y = vv.y*scb[c+1] + shb[c+1];
    vv.z = vv.z*scb[c+2] + shb[c+2];
    vv.w = vv.w*scb[c+3] + shb[c+3];
    ((float4*)a.outp)[i] = vv;
  }
}

extern "C" void kernel_launch(void* const* d_in, const int* in_sizes, int n_in,
                              void* d_out, int out_size, void* d_ws, size_t ws_size,
                              hipStream_t stream) {
  const float* q   = (const float*)d_in[0];
  const float* k   = (const float*)d_in[1];
  const float* v   = (const float*)d_in[2];
  const float* ef  = (const float*)d_in[3];
  const int*   src = (const int*)d_in[4];
  const int*   dst = (const int*)d_in[5];
  const float* Wq  = (const float*)d_in[6];
  const float* Wk  = (const float*)d_in[7];
  const float* Wv  = (const float*)d_in[8];
  const float* We  = (const float*)d_in[9];
  const float* be  = (const float*)d_in[10];
  const float* Wo  = (const float*)d_in[11];
  const float* W1  = (const float*)d_in[12];
  const float* b1  = (const float*)d_in[13];
  const float* W2  = (const float*)d_in[14];
  const float* b2  = (const float*)d_in[15];
  const float* g1  = (const float*)d_in[16];
  const float* bt1 = (const float*)d_in[17];
  const float* g2  = (const float*)d_in[18];
  const float* bt2 = (const float*)d_in[19];
  float* out = (float*)d_out;

  // ---- workspace layout (float units); NB = N*128 = 5.12M ----
  float* ws = (float*)d_ws;
  const size_t NB = (size_t)Nn * CC;            // 5,120,000
  float* QDb = ws;
  float* Kb  = ws + NB/2;
  float* Vb  = ws + NB;
  unsigned* KVq = (unsigned*)(ws + 3*NB/2);
  unsigned short* EBs = (unsigned short*)(ws + 2*NB);
  unsigned* AGGb = (unsigned*)(ws + 5*NB/2);
  float* Y   = ws + 5*NB/2;     // overlays AGGb (dead by FFN2)
  float* RST = ws + 7*NB/2;
  float* H1  = ws;              // [N,256] bf16 overlays QDb+Kb (dead by FFN1)
  float* bn = ws + 9*NB/2;
  float* sum1 = bn;       float* sq1 = bn+128;
  float* sum2 = bn+512;   float* sq2 = bn+640;
  int* bars   = (int*)(bn + 768);       // 8 counters, zeroed by prep_k
  int* ib      = (int*)(bn + 1024);
  int* counts  = ib;                    // 40000
  int* offsets = ib + 40000;            // 40001
  int* cursor  = ib + 80001;            // 40000
  int* posA    = ib + 120001;           // 640000
  int* srcsA   = ib + 760001;           // 640000
  int* bsums   = ib + 1400001;          // 64
  unsigned short* Wb = (unsigned short*)(ib + 1400068);  // 16B-aligned bf16 weights
  unsigned short* WqB = Wb;
  unsigned short* WkB = Wb + 16384;
  unsigned short* WvB = Wb + 32768;
  unsigned short* WoB = Wb + 49152;
  unsigned short* W1B = Wb + 65536;
  unsigned short* W2B = Wb + 98304;

  // launch 1: zero bn scratch + barrier counters (bn+768..776) + counts; weights->bf16
  prep_k<<<dim3(673), 256, 0, stream>>>((int*)bn, 1024 + Nn,
                                        Wq, Wk, Wv, Wo, W1, W2, Wb);

  // launch 2: persistent CSR + projection (hist/scan/scatter/proj)
  {
    CsrArgs ca;
    ca.dst = dst; ca.src = src;
    ca.counts = counts; ca.offsets = offsets; ca.cursor = cursor;
    ca.posA = posA; ca.srcs = srcsA; ca.bsums = bsums; ca.bars = bars;
    ca.q = q; ca.k = k; ca.v = v;
    ca.WqB = WqB; ca.WkB = WkB; ca.WvB = WvB;
    ca.QDb = QDb; ca.Kb = Kb; ca.Vb = Vb;
    csr_k<<<dim3(512), 256, 0, stream>>>(ca);
  }

  // launch 3: merged repack (coalesced fp8 KV) + ebias (CSR-order bias table)
  re_k<<<dim3(30000), 256, 0, stream>>>((const unsigned*)Kb, (const unsigned*)Vb,
                                        KVq, ef, We, be, posA, EBs);

  // launch 4: fused scores + segment softmax + aggregation -> bf16 AGG
  agg_k<<<dim3(Nn/4), 256, 0, stream>>>((const unsigned*)QDb, KVq, EBs,
                                        offsets, srcsA, AGGb, Nn);

  // launch 5: persistent tail (Wo + BN1 + FFN1 + FFN2 + BN2 apply)
  {
    TailArgs ta;
    ta.AGGb = AGGb; ta.WoB = WoB; ta.RST = RST; ta.q = q;
    ta.W1B = W1B; ta.H1 = H1; ta.b1 = b1;
    ta.W2B = W2B; ta.Y = Y; ta.b2 = b2;
    ta.sum1 = sum1; ta.sq1 = sq1; ta.sum2 = sum2; ta.sq2 = sq2;
    ta.g1 = g1; ta.bt1 = bt1; ta.g2 = g2; ta.bt2 = bt2;
    ta.outp = out; ta.bars = bars + 3;
    tail_k<<<dim3(512), 256, 0, stream>>>(ta);
  }
}